// Round 4
// baseline (15030.132 us; speedup 1.0000x reference)
//
#include <hip/hip_runtime.h>
#include <math.h>

#define T_STEPS 4096
#define HDIM    2048
#define KDIM    2048
#define NG      8192      // 4*H
#define CTR_STRIDE 16     // uints: one 64B line per counter
#define NREC    2048      // records per slot: one {h,tag} per h element

typedef unsigned long long ull;

// ---------------- init ----------------
// ctr[8] (64B apart): monotonic hint counters, seeded 32 (= "h0 published").
// recs[2][NREC]: tagged h records, 8B each: {lo: h bits, hi: tag}.
// tag convention: producer of step t writes tag t+1; consumer at step t
// expects tag t in its read slot. Slot 1 = h0 (tag 0); slot 0 = sentinel.
__global__ void init_ws4(const float* __restrict__ h0,
                         unsigned* __restrict__ ctr,    // [8*CTR_STRIDE]
                         uint2* __restrict__ recs) {    // [2][NREC]
    int g = blockIdx.x * blockDim.x + threadIdx.x;
    if (g < 8 * CTR_STRIDE) ctr[g] = ((g % CTR_STRIDE) == 0) ? 32u : 0u;
    int d = g - 8 * CTR_STRIDE;
    if (d >= 0 && d < 2 * NREC) {
        int slot = d >> 11;
        int r = d & (NREC - 1);
        uint2 v;
        if (slot == 1) {
            v.x = __float_as_uint(h0[r]);
            v.y = 0u;                      // tag 0 = "published by step -1"
        } else {
            v.x = 0u;
            v.y = 0xFFFFFFFFu;             // never matches any expected tag
        }
        recs[d] = v;
    }
}

// ---------------- Phase 1: Y = X @ Wi + bias (fp32 tiled GEMM) ----------------
__global__ __launch_bounds__(256) void gemm_xwi(
    const float* __restrict__ X, const float* __restrict__ Wi,
    const float* __restrict__ bias, float* __restrict__ Y)
{
    __shared__ float As[16][65];
    __shared__ __align__(16) float Bs[16][64];
    const int tid = threadIdx.x;
    const int m0 = blockIdx.y * 64;
    const int n0 = blockIdx.x * 64;
    const int tx4 = (tid & 15) * 4;
    const int ty4 = (tid >> 4) * 4;
    const int am = tid >> 2, ak = (tid & 3) * 4;
    const int bk = tid >> 4, bn = (tid & 15) * 4;

    float acc[4][4];
#pragma unroll
    for (int i = 0; i < 4; ++i)
#pragma unroll
        for (int j = 0; j < 4; ++j) acc[i][j] = 0.f;

    for (int kt = 0; kt < KDIM; kt += 16) {
        float4 av = *reinterpret_cast<const float4*>(&X[(size_t)(m0 + am) * KDIM + kt + ak]);
        float4 bv = *reinterpret_cast<const float4*>(&Wi[(size_t)(kt + bk) * NG + n0 + bn]);
        __syncthreads();
        As[ak + 0][am] = av.x; As[ak + 1][am] = av.y;
        As[ak + 2][am] = av.z; As[ak + 3][am] = av.w;
        *reinterpret_cast<float4*>(&Bs[bk][bn]) = bv;
        __syncthreads();
#pragma unroll
        for (int k = 0; k < 16; ++k) {
            float a0 = As[k][ty4 + 0], a1 = As[k][ty4 + 1];
            float a2 = As[k][ty4 + 2], a3 = As[k][ty4 + 3];
            float4 b4 = *reinterpret_cast<const float4*>(&Bs[k][tx4]);
            acc[0][0] = fmaf(a0, b4.x, acc[0][0]); acc[0][1] = fmaf(a0, b4.y, acc[0][1]);
            acc[0][2] = fmaf(a0, b4.z, acc[0][2]); acc[0][3] = fmaf(a0, b4.w, acc[0][3]);
            acc[1][0] = fmaf(a1, b4.x, acc[1][0]); acc[1][1] = fmaf(a1, b4.y, acc[1][1]);
            acc[1][2] = fmaf(a1, b4.z, acc[1][2]); acc[1][3] = fmaf(a1, b4.w, acc[1][3]);
            acc[2][0] = fmaf(a2, b4.x, acc[2][0]); acc[2][1] = fmaf(a2, b4.y, acc[2][1]);
            acc[2][2] = fmaf(a2, b4.z, acc[2][2]); acc[2][3] = fmaf(a2, b4.w, acc[2][3]);
            acc[3][0] = fmaf(a3, b4.x, acc[3][0]); acc[3][1] = fmaf(a3, b4.y, acc[3][1]);
            acc[3][2] = fmaf(a3, b4.z, acc[3][2]); acc[3][3] = fmaf(a3, b4.w, acc[3][3]);
        }
    }
    float4 bb = *reinterpret_cast<const float4*>(&bias[n0 + tx4]);
#pragma unroll
    for (int i = 0; i < 4; ++i) {
        float4 o;
        o.x = acc[i][0] + bb.x; o.y = acc[i][1] + bb.y;
        o.z = acc[i][2] + bb.z; o.w = acc[i][3] + bb.w;
        *reinterpret_cast<float4*>(&Y[(size_t)(m0 + ty4 + i) * NG + n0 + tx4]) = o;
    }
}

// ---------------- fast activations ----------------
__device__ __forceinline__ float fsigm(float x) { return 1.f / (1.f + __expf(-x)); }
__device__ __forceinline__ float ftanh(float x) {
    float ax = fabsf(x);
    float e  = __expf(2.f * ax);
    float t  = (e - 1.f) / (e + 1.f);
    t = (ax > 15.f) ? 1.f : t;
    return copysignf(t, x);
}

// ---------------- Phase 2: persistent recurrent kernel ----------------
// 256 blocks x 512 threads, cooperative, 1 block/CU.
//
// ROUND 4 change (isolated): weights pinned in AGPRs by construction.
// Rounds 2/3 proved the compiler will NOT keep a 128-float weight array
// in arch VGPRs (VGPR_Count stayed 84/88; per-step spill-refetch of
// 64 MB chip-wide was ~2/3 of the step time). Values defined via
// asm "=a" (v_accvgpr_write_b32) and read via asm "a" inputs are
// AGPR-class virtual regs: RA must color them into the 170+ free AGPRs
// of the unified file (256 unified regs/wave at 2 waves/EU) and has no
// cheaper spill class. Cost: 128 v_accvgpr_read + 128 fma per thread per
// step (~0.2us) instead of a 512 B/thread memory walk (~2us).
//
// Publication protocol (unchanged): h published as eight self-validating
// 8B records {h, tag=t+1} via single global_store_dwordx2 sc0sc1
// (single-copy atomic). Counter atomicAdd is a HINT with NO vmcnt release
// drain. Consumers poll the 8 hint counters, then load records and VERIFY
// tags, retrying on stale. Lap safety: increment-after-read is
// same-thread program order.
__global__ __launch_bounds__(512)
__attribute__((amdgpu_waves_per_eu(2, 2)))
void lstm_persistent(
    const float* __restrict__ Y,     // [T][NG]
    const float* __restrict__ c0,
    const float* __restrict__ Wh,    // [K][NG]
    uint2* __restrict__ recs,        // [2][NREC] tagged h records
    unsigned* __restrict__ ctr,      // [8*CTR_STRIDE]
    float* __restrict__ out)         // [c_f][h_f][ys]
{
    const int b    = blockIdx.x;
    const int tid  = threadIdx.x;
    const int lane = tid & 63;
    const int w    = tid >> 6;       // 0..7
    const int gg   = w >> 1;
    const int hg   = w & 1;
    const int nbase = (gg << 11) + (b << 3) + (hg << 2);

    __shared__ __align__(16) float hlds[HDIM];   // 8 KiB staging
    __shared__ float gates[32];
    __shared__ float c_s[8];
    __shared__ float hlast[8];
    __shared__ unsigned ldsflag;

    // ---- load weight slice once, pin into AGPRs ----
    // wa[(4j+m)*4 + c] = Wh[(4*lane + 256*j + m)][nbase + c]
    // (multiplies h4 component m, accumulates into acc component c)
    float wa[128];
#pragma unroll
    for (int j = 0; j < 8; ++j)
#pragma unroll
        for (int m = 0; m < 4; ++m) {
            const size_t k = (size_t)(4 * lane + 256 * j + m);
            float4 wv = *reinterpret_cast<const float4*>(&Wh[k * NG + nbase]);
            const int base = (j * 4 + m) * 4;
            asm volatile("v_accvgpr_write_b32 %0, %1" : "=a"(wa[base + 0]) : "v"(wv.x));
            asm volatile("v_accvgpr_write_b32 %0, %1" : "=a"(wa[base + 1]) : "v"(wv.y));
            asm volatile("v_accvgpr_write_b32 %0, %1" : "=a"(wa[base + 2]) : "v"(wv.z));
            asm volatile("v_accvgpr_write_b32 %0, %1" : "=a"(wa[base + 3]) : "v"(wv.w));
        }

    if (tid < 8) c_s[tid] = c0[b * 8 + tid];
    if (tid == 0) ldsflag = 0xFFFFFFFFu;
    __syncthreads();

    for (int t = 0; t < T_STEPS; ++t) {
        const int rs = (t + 1) & 1;          // read slot (h input of step t)
        const unsigned target = 32u * (unsigned)(t + 1);

        // Y prefetch (hidden under the wait)
        float yv = 0.f;
        if (lane < 4) yv = Y[(size_t)t * NG + nbase + lane];

        // ---- hint detect: wave 0 polls 8 counters; others spin on LDS ----
        if (w == 0) {
            const unsigned* cp = ctr + (size_t)(lane & 7) * CTR_STRIDE;
            for (;;) {
                unsigned v = target;
                if (lane < 8)
                    v = __hip_atomic_load(cp, __ATOMIC_RELAXED, __HIP_MEMORY_SCOPE_SYSTEM);
                if (__all(v >= target)) break;
                __builtin_amdgcn_s_sleep(1);
            }
            if (lane == 0)
                __hip_atomic_store(&ldsflag, (unsigned)t, __ATOMIC_RELEASE,
                                   __HIP_MEMORY_SCOPE_WORKGROUP);
        } else {
            while (__hip_atomic_load(&ldsflag, __ATOMIC_ACQUIRE,
                                     __HIP_MEMORY_SCOPE_WORKGROUP) != (unsigned)t)
                __builtin_amdgcn_s_sleep(1);
        }

        // ---- tagged record load: 2x16B per thread (= 2x2 records),
        //      verify all 4 tags, retry if any stale ----
        {
            const uint2* rb = recs + (size_t)rs * NREC;
            const uint2* p0 = rb + 2 * tid;          // records 2t, 2t+1
            const uint2* p1 = rb + 1024 + 2 * tid;   // records 1024+2t, +1
            const unsigned expt = (unsigned)t;
            uint4 ra, rc;   // {h_a, tag_a, h_b, tag_b}
            for (;;) {
                asm volatile("global_load_dwordx4 %0, %2, off sc0 sc1\n\t"
                             "global_load_dwordx4 %1, %3, off sc0 sc1\n\t"
                             "s_waitcnt vmcnt(0)"
                             : "=&v"(ra), "=&v"(rc)
                             : "v"(p0), "v"(p1) : "memory");
                if (__all((ra.y == expt) & (ra.w == expt) &
                          (rc.y == expt) & (rc.w == expt))) break;
                __builtin_amdgcn_s_sleep(1);
            }
            float2 d0; d0.x = __uint_as_float(ra.x); d0.y = __uint_as_float(ra.z);
            float2 d1; d1.x = __uint_as_float(rc.x); d1.y = __uint_as_float(rc.z);
            *reinterpret_cast<float2*>(&hlds[2 * tid])        = d0;
            *reinterpret_cast<float2*>(&hlds[1024 + 2 * tid]) = d1;
        }
        __syncthreads();   // all of h staged

        // ---- 128 FMAs on AGPR-resident weights ----
        float4 acc; acc.x = acc.y = acc.z = acc.w = 0.f;
#pragma unroll
        for (int j = 0; j < 8; ++j) {
            float4 h4 = reinterpret_cast<const float4*>(hlds)[lane + 64 * j];
            const int base = 16 * j;
#pragma unroll
            for (int m = 0; m < 4; ++m) {
                const float hm = (m == 0) ? h4.x : (m == 1) ? h4.y
                               : (m == 2) ? h4.z : h4.w;
                float w0, w1, w2, w3;
                asm volatile("v_accvgpr_read_b32 %0, %1" : "=v"(w0) : "a"(wa[base + m * 4 + 0]));
                asm volatile("v_accvgpr_read_b32 %0, %1" : "=v"(w1) : "a"(wa[base + m * 4 + 1]));
                asm volatile("v_accvgpr_read_b32 %0, %1" : "=v"(w2) : "a"(wa[base + m * 4 + 2]));
                asm volatile("v_accvgpr_read_b32 %0, %1" : "=v"(w3) : "a"(wa[base + m * 4 + 3]));
                acc.x = fmaf(hm, w0, acc.x);
                acc.y = fmaf(hm, w1, acc.y);
                acc.z = fmaf(hm, w2, acc.z);
                acc.w = fmaf(hm, w3, acc.w);
            }
        }
#pragma unroll
        for (int off = 32; off >= 1; off >>= 1) {
            acc.x += __shfl_xor(acc.x, off);
            acc.y += __shfl_xor(acc.y, off);
            acc.z += __shfl_xor(acc.z, off);
            acc.w += __shfl_xor(acc.w, off);
        }
        if (lane < 4) {
            float v = (lane == 0) ? acc.x : (lane == 1) ? acc.y
                    : (lane == 2) ? acc.z : acc.w;
            gates[gg * 8 + hg * 4 + lane] = v + yv;
        }
        __syncthreads();   // gates ready; all hlds reads of step t done

        // ---- epilogue: tagged 8B publish, NO release drain, hint add ----
        if (tid < 8) {
            float iv = gates[0 * 8 + tid];
            float fv = gates[1 * 8 + tid];
            float gv = gates[2 * 8 + tid];
            float ov = gates[3 * 8 + tid];
            float cn = fsigm(fv) * c_s[tid] + fsigm(iv) * ftanh(gv);
            float hn = fsigm(ov) * ftanh(cn);
            c_s[tid] = cn;
            hlast[tid] = hn;
            // {lo: h bits, hi: tag t+1} -> one 64b store, single-copy atomic
            ull rec = ((ull)(unsigned)(t + 1) << 32) | (ull)__float_as_uint(hn);
            uint2* dst = recs + (size_t)(t & 1) * NREC + b * 8 + tid;
            asm volatile("global_store_dwordx2 %0, %1, off sc0 sc1"
                         :: "v"(dst), "v"(rec) : "memory");
            if (tid == 0)
                __hip_atomic_fetch_add(ctr + (size_t)(b >> 5) * CTR_STRIDE, 1u,
                                       __ATOMIC_RELAXED, __HIP_MEMORY_SCOPE_SYSTEM);
            __builtin_nontemporal_store(hn, &out[2 * HDIM + (size_t)t * HDIM + b * 8 + tid]);
        }
    }

    if (tid < 8) {
        out[b * 8 + tid]        = c_s[tid];   // c_f
        out[HDIM + b * 8 + tid] = hlast[tid]; // h_f
    }
}

// ---------------- launch ----------------
extern "C" void kernel_launch(void* const* d_in, const int* in_sizes, int n_in,
                              void* d_out, int out_size, void* d_ws, size_t ws_size,
                              hipStream_t stream) {
    const float* x   = (const float*)d_in[0];
    const float* c0  = (const float*)d_in[1];
    const float* h0  = (const float*)d_in[2];
    const float* Wi  = (const float*)d_in[3];
    const float* Wh  = (const float*)d_in[4];
    const float* bia = (const float*)d_in[5];
    float* out = (float*)d_out;

    char* base = (char*)d_ws;
    float* Y = (float*)base;                                  // 128 MiB
    base += (size_t)T_STEPS * NG * sizeof(float);
    unsigned* ctr = (unsigned*)base;                          // 512 B
    base += 8 * CTR_STRIDE * sizeof(unsigned);
    uint2* recs = (uint2*)base;                               // 32 KiB

    const int initN = 8 * CTR_STRIDE + 2 * NREC;
    hipLaunchKernelGGL(init_ws4, dim3((initN + 511) / 512), dim3(512), 0, stream,
                       h0, ctr, recs);
    hipLaunchKernelGGL(gemm_xwi, dim3(NG / 64, T_STEPS / 64), dim3(256), 0, stream,
                       x, Wi, bia, Y);

    void* args[] = { (void*)&Y, (void*)&c0, (void*)&Wh,
                     (void*)&recs, (void*)&ctr, (void*)&out };
    (void)hipLaunchCooperativeKernel((const void*)lstm_persistent, dim3(256), dim3(512),
                                     args, 0, stream);
}

// Round 5
// 13915.536 us; speedup vs baseline: 1.0801x; 1.0801x over previous
//
#include <hip/hip_runtime.h>
#include <math.h>

#define T_STEPS 4096
#define HDIM    2048
#define KDIM    2048
#define NG      8192      // 4*H
#define NREC    2048      // records per slot: one {h,tag} per h element
#define NSLOT   3         // 3-slot rotation (lap safety without counters)

typedef unsigned long long ull;

// ---------------- init ----------------
// recs[3][NREC]: tagged h records, 8B each: {lo: h bits, hi: tag}.
// Producer of step t writes tag t+1 into slot t%3; consumer at step t
// polls slot (t-1)%3 for tag t. Slot 2 = h0 (tag 0, "step -1" output);
// slots 0,1 = sentinel (never matches an expected tag).
__global__ void init_ws5(const float* __restrict__ h0,
                         uint2* __restrict__ recs) {    // [NSLOT][NREC]
    int d = blockIdx.x * blockDim.x + threadIdx.x;
    if (d < NSLOT * NREC) {
        int slot = d >> 11;          // NREC = 2048
        int r = d & (NREC - 1);
        uint2 v;
        if (slot == 2) {
            v.x = __float_as_uint(h0[r]);
            v.y = 0u;                      // tag 0
        } else {
            v.x = 0u;
            v.y = 0xFFFFFFFFu;             // sentinel
        }
        recs[d] = v;
    }
}

// ---------------- Phase 1: Y = X @ Wi + bias (fp32 tiled GEMM) ----------------
__global__ __launch_bounds__(256) void gemm_xwi(
    const float* __restrict__ X, const float* __restrict__ Wi,
    const float* __restrict__ bias, float* __restrict__ Y)
{
    __shared__ float As[16][65];
    __shared__ __align__(16) float Bs[16][64];
    const int tid = threadIdx.x;
    const int m0 = blockIdx.y * 64;
    const int n0 = blockIdx.x * 64;
    const int tx4 = (tid & 15) * 4;
    const int ty4 = (tid >> 4) * 4;
    const int am = tid >> 2, ak = (tid & 3) * 4;
    const int bk = tid >> 4, bn = (tid & 15) * 4;

    float acc[4][4];
#pragma unroll
    for (int i = 0; i < 4; ++i)
#pragma unroll
        for (int j = 0; j < 4; ++j) acc[i][j] = 0.f;

    for (int kt = 0; kt < KDIM; kt += 16) {
        float4 av = *reinterpret_cast<const float4*>(&X[(size_t)(m0 + am) * KDIM + kt + ak]);
        float4 bv = *reinterpret_cast<const float4*>(&Wi[(size_t)(kt + bk) * NG + n0 + bn]);
        __syncthreads();
        As[ak + 0][am] = av.x; As[ak + 1][am] = av.y;
        As[ak + 2][am] = av.z; As[ak + 3][am] = av.w;
        *reinterpret_cast<float4*>(&Bs[bk][bn]) = bv;
        __syncthreads();
#pragma unroll
        for (int k = 0; k < 16; ++k) {
            float a0 = As[k][ty4 + 0], a1 = As[k][ty4 + 1];
            float a2 = As[k][ty4 + 2], a3 = As[k][ty4 + 3];
            float4 b4 = *reinterpret_cast<const float4*>(&Bs[k][tx4]);
            acc[0][0] = fmaf(a0, b4.x, acc[0][0]); acc[0][1] = fmaf(a0, b4.y, acc[0][1]);
            acc[0][2] = fmaf(a0, b4.z, acc[0][2]); acc[0][3] = fmaf(a0, b4.w, acc[0][3]);
            acc[1][0] = fmaf(a1, b4.x, acc[1][0]); acc[1][1] = fmaf(a1, b4.y, acc[1][1]);
            acc[1][2] = fmaf(a1, b4.z, acc[1][2]); acc[1][3] = fmaf(a1, b4.w, acc[1][3]);
            acc[2][0] = fmaf(a2, b4.x, acc[2][0]); acc[2][1] = fmaf(a2, b4.y, acc[2][1]);
            acc[2][2] = fmaf(a2, b4.z, acc[2][2]); acc[2][3] = fmaf(a2, b4.w, acc[2][3]);
            acc[3][0] = fmaf(a3, b4.x, acc[3][0]); acc[3][1] = fmaf(a3, b4.y, acc[3][1]);
            acc[3][2] = fmaf(a3, b4.z, acc[3][2]); acc[3][3] = fmaf(a3, b4.w, acc[3][3]);
        }
    }
    float4 bb = *reinterpret_cast<const float4*>(&bias[n0 + tx4]);
#pragma unroll
    for (int i = 0; i < 4; ++i) {
        float4 o;
        o.x = acc[i][0] + bb.x; o.y = acc[i][1] + bb.y;
        o.z = acc[i][2] + bb.z; o.w = acc[i][3] + bb.w;
        *reinterpret_cast<float4*>(&Y[(size_t)(m0 + ty4 + i) * NG + n0 + tx4]) = o;
    }
}

// ---------------- fast activations ----------------
__device__ __forceinline__ float fsigm(float x) { return 1.f / (1.f + __expf(-x)); }
__device__ __forceinline__ float ftanh(float x) {
    float ax = fabsf(x);
    float e  = __expf(2.f * ax);
    float t  = (e - 1.f) / (e + 1.f);
    t = (ax > 15.f) ? 1.f : t;
    return copysignf(t, x);
}

// ---------------- Phase 2: persistent recurrent kernel ----------------
// 256 blocks x 512 threads, cooperative, 1 block/CU.
//
// ROUND 5 (isolated sync change; compute reverted to round-3 best):
// Counters + wave0-poll + LDS-flag relay REMOVED. The records are
// self-validating, so detect is merged into fetch: every thread directly
// tag-polls its own 32B of the record set (131072 poll lanes on a 16KB
// MALL-resident set, s_sleep(1) backoff -> ~1-2 sweeps steady-state).
// This cuts the counter MALL RTT + flag relay out of the per-step chain.
//
// Lap safety WITHOUT counters requires 3 slots. Proof: writes to slot s
// carry tags t, t+3, ... While block Z polls slot s at step t (expect
// tag t), block X writes tag t+3 into s only at its step t+2, reached
// only after X's step-t+1 read saw ALL tag-t+1 records -- including Z's,
// which Z publishes only AFTER its step-t reads complete (program
// order). So Z sees only stale (<t, retry) or exact tag t. QED.
//
// Publication: eight 8B records {h, tag=t+1} via global_store_dwordx2
// sc0sc1 (aligned 64b store = single-copy atomic), fire-and-forget, no
// release drain.
__global__ __launch_bounds__(512)
__attribute__((amdgpu_waves_per_eu(2, 2)))
void lstm_persistent(
    const float* __restrict__ Y,     // [T][NG]
    const float* __restrict__ c0,
    const float* __restrict__ Wh,    // [K][NG]
    uint2* __restrict__ recs,        // [NSLOT][NREC] tagged h records
    float* __restrict__ out)         // [c_f][h_f][ys]
{
    const int b    = blockIdx.x;
    const int tid  = threadIdx.x;
    const int lane = tid & 63;
    const int w    = tid >> 6;       // 0..7
    const int gg   = w >> 1;
    const int hg   = w & 1;
    const int nbase = (gg << 11) + (b << 3) + (hg << 2);

    __shared__ __align__(16) float hlds[HDIM];   // 8 KiB staging
    __shared__ float gates[32];
    __shared__ float c_s[8];
    __shared__ float hlast[8];

    // ---- load weight slice once (round-3 compute form, empirical best) ----
    float4 wreg[32];
#pragma unroll
    for (int j = 0; j < 8; ++j)
#pragma unroll
        for (int m = 0; m < 4; ++m) {
            const size_t k = (size_t)(4 * lane + 256 * j + m);
            wreg[j * 4 + m] = *reinterpret_cast<const float4*>(&Wh[k * NG + nbase]);
        }
#pragma unroll
    for (int i = 0; i < 32; ++i) {
        asm volatile("" : "+v"(wreg[i].x), "+v"(wreg[i].y),
                          "+v"(wreg[i].z), "+v"(wreg[i].w));
    }

    if (tid < 8) c_s[tid] = c0[b * 8 + tid];
    __syncthreads();

    int rs = 2;   // read slot for step t = (t-1) mod 3 ; t=0 -> 2
    int ws = 0;   // write slot for step t = t mod 3

    for (int t = 0; t < T_STEPS; ++t) {
        // Y prefetch (hidden under the poll)
        float yv = 0.f;
        if (lane < 4) yv = Y[(size_t)t * NG + nbase + lane];

        // ---- fused detect+fetch: tag-poll own 2x16B (= 4 records) ----
        {
            const uint2* rb = recs + (size_t)rs * NREC;
            const uint2* p0 = rb + 2 * tid;          // records 2tid, 2tid+1
            const uint2* p1 = rb + 1024 + 2 * tid;   // records 1024+2tid, +1
            const unsigned expt = (unsigned)t;
            uint4 ra, rc;   // {h_a, tag_a, h_b, tag_b}
            for (;;) {
                asm volatile("global_load_dwordx4 %0, %2, off sc0 sc1\n\t"
                             "global_load_dwordx4 %1, %3, off sc0 sc1\n\t"
                             "s_waitcnt vmcnt(0)"
                             : "=&v"(ra), "=&v"(rc)
                             : "v"(p0), "v"(p1) : "memory");
                if (__all((ra.y == expt) & (ra.w == expt) &
                          (rc.y == expt) & (rc.w == expt))) break;
                __builtin_amdgcn_s_sleep(1);
            }
            float2 d0; d0.x = __uint_as_float(ra.x); d0.y = __uint_as_float(ra.z);
            float2 d1; d1.x = __uint_as_float(rc.x); d1.y = __uint_as_float(rc.z);
            *reinterpret_cast<float2*>(&hlds[2 * tid])        = d0;
            *reinterpret_cast<float2*>(&hlds[1024 + 2 * tid]) = d1;
        }
        __syncthreads();   // all of h staged

        // ---- 128 FMAs on weight slice ----
        float4 acc; acc.x = acc.y = acc.z = acc.w = 0.f;
#pragma unroll
        for (int j = 0; j < 8; ++j) {
            float4 h4 = reinterpret_cast<const float4*>(hlds)[lane + 64 * j];
            float4 w0 = wreg[4 * j + 0], w1 = wreg[4 * j + 1];
            float4 w2 = wreg[4 * j + 2], w3 = wreg[4 * j + 3];
            acc.x = fmaf(h4.x, w0.x, acc.x); acc.x = fmaf(h4.y, w1.x, acc.x);
            acc.x = fmaf(h4.z, w2.x, acc.x); acc.x = fmaf(h4.w, w3.x, acc.x);
            acc.y = fmaf(h4.x, w0.y, acc.y); acc.y = fmaf(h4.y, w1.y, acc.y);
            acc.y = fmaf(h4.z, w2.y, acc.y); acc.y = fmaf(h4.w, w3.y, acc.y);
            acc.z = fmaf(h4.x, w0.z, acc.z); acc.z = fmaf(h4.y, w1.z, acc.z);
            acc.z = fmaf(h4.z, w2.z, acc.z); acc.z = fmaf(h4.w, w3.z, acc.z);
            acc.w = fmaf(h4.x, w0.w, acc.w); acc.w = fmaf(h4.y, w1.w, acc.w);
            acc.w = fmaf(h4.z, w2.w, acc.w); acc.w = fmaf(h4.w, w3.w, acc.w);
        }
#pragma unroll
        for (int off = 32; off >= 1; off >>= 1) {
            acc.x += __shfl_xor(acc.x, off);
            acc.y += __shfl_xor(acc.y, off);
            acc.z += __shfl_xor(acc.z, off);
            acc.w += __shfl_xor(acc.w, off);
        }
        if (lane < 4) {
            float v = (lane == 0) ? acc.x : (lane == 1) ? acc.y
                    : (lane == 2) ? acc.z : acc.w;
            gates[gg * 8 + hg * 4 + lane] = v + yv;
        }
        __syncthreads();   // gates ready; all hlds reads of step t done

        // ---- epilogue: tagged 8B publish, fire-and-forget ----
        if (tid < 8) {
            float iv = gates[0 * 8 + tid];
            float fv = gates[1 * 8 + tid];
            float gv = gates[2 * 8 + tid];
            float ov = gates[3 * 8 + tid];
            float cn = fsigm(fv) * c_s[tid] + fsigm(iv) * ftanh(gv);
            float hn = fsigm(ov) * ftanh(cn);
            c_s[tid] = cn;
            hlast[tid] = hn;
            // {lo: h bits, hi: tag t+1} -> one 64b store, single-copy atomic
            ull rec = ((ull)(unsigned)(t + 1) << 32) | (ull)__float_as_uint(hn);
            uint2* dst = recs + (size_t)ws * NREC + b * 8 + tid;
            asm volatile("global_store_dwordx2 %0, %1, off sc0 sc1"
                         :: "v"(dst), "v"(rec) : "memory");
            __builtin_nontemporal_store(hn, &out[2 * HDIM + (size_t)t * HDIM + b * 8 + tid]);
        }

        rs = ws;
        ws = (ws == 2) ? 0 : ws + 1;
    }

    if (tid < 8) {
        out[b * 8 + tid]        = c_s[tid];   // c_f
        out[HDIM + b * 8 + tid] = hlast[tid]; // h_f
    }
}

// ---------------- launch ----------------
extern "C" void kernel_launch(void* const* d_in, const int* in_sizes, int n_in,
                              void* d_out, int out_size, void* d_ws, size_t ws_size,
                              hipStream_t stream) {
    const float* x   = (const float*)d_in[0];
    const float* c0  = (const float*)d_in[1];
    const float* h0  = (const float*)d_in[2];
    const float* Wi  = (const float*)d_in[3];
    const float* Wh  = (const float*)d_in[4];
    const float* bia = (const float*)d_in[5];
    float* out = (float*)d_out;

    char* base = (char*)d_ws;
    float* Y = (float*)base;                                  // 128 MiB
    base += (size_t)T_STEPS * NG * sizeof(float);
    uint2* recs = (uint2*)base;                               // 48 KiB

    const int initN = NSLOT * NREC;
    hipLaunchKernelGGL(init_ws5, dim3((initN + 511) / 512), dim3(512), 0, stream,
                       h0, recs);
    hipLaunchKernelGGL(gemm_xwi, dim3(NG / 64, T_STEPS / 64), dim3(256), 0, stream,
                       x, Wi, bia, Y);

    void* args[] = { (void*)&Y, (void*)&c0, (void*)&Wh,
                     (void*)&recs, (void*)&out };
    (void)hipLaunchCooperativeKernel((const void*)lstm_persistent, dim3(256), dim3(512),
                                     args, 0, stream);
}